// Round 14
// baseline (13965.312 us; speedup 1.0000x reference)
//
#include <hip/hip_runtime.h>

// Recurrent spiking LIF network: T=64, B=32, NE=4096, NI=1024, N=5120.
// fp64 accumulation => spike-identical to fp64 numpy ref (rounds 2-13: 0.0).
//
// Round-14: ONE fused kernel per step (64 launches, was 192).
//  - mv core = round-13 (weights staged via global_load_lds, spikes as
//    bitmask in SGPRs, dense bit->f64 fma), G=32, CHUNK=32 -> 16 KB LDS,
//    grid (40,32) = 1280 blocks = exactly 5/CU (occupancy cap 62%).
//  - last-block-wins reduction: per column, the 32nd block to finish
//    sums partials, does the LIF update, writes out, and builds the
//    next-step spike bitmask (LDS OR). upd+pack kernels eliminated;
//    their work overlaps with other columns' mv.
//  - masks double-buffered (read t-1 / write t): no intra-launch race.
//  - deterministic: fixed g-order reduction; atomics only pick WHO reduces.

#define NE 4096
#define NI 1024
#define NN 5120
#define HN 2560
#define BB 32
#define CHUNK 32
#define NCOL 40      // HN/64 columns; each covers n in [c*64,+64) u [HN+c*64,+64)

typedef unsigned int u32;

__device__ __forceinline__ void load_lds16(const float* g, float* l) {
    __builtin_amdgcn_global_load_lds(
        (const __attribute__((address_space(1))) u32*)g,
        (__attribute__((address_space(3))) u32*)l, 16, 0, 0);
}

// grid: (NCOL, G), block 256 = 64 n-lanes x 4 j-groups(8 batches).
template <int G>
__global__ __launch_bounds__(256) void step_kernel(
    const float* __restrict__ W_ee, const float* __restrict__ W_ei,
    const float* __restrict__ W_ie, const float* __restrict__ W_ii,
    const float* __restrict__ ext_exc,   // [T][BB][NE]
    const float* __restrict__ ext_inh,   // [T][BB][NI]
    const u32* __restrict__ maskIn,      // [NN] spikes of step t-1
    u32* __restrict__ maskOut,           // [NN] spikes of step t
    double* __restrict__ partial,        // [G][BB][NN]
    double* __restrict__ v,              // [BB][NN]
    float* __restrict__ out,             // [T][BB][NN]
    int* __restrict__ cnt,               // [T][NCOL]
    int t)
{
    constexpr int KR = NN / G;
    __shared__ __align__(16) float tile[16 * 256];   // 16 slots x 64 lanes x 16B
    __shared__ u32 s_m[128];
    __shared__ int s_won;

    const int tid  = threadIdx.x;
    const int lane = tid & 63;
    const int wv   = tid >> 6;
    const int jh   = wv << 3;                  // 0,8,16,24
    const int col  = blockIdx.x;
    const int g    = blockIdx.y;
    const int nA   = col * 64 + lane;          // < HN (E-target half)
    const int kb0  = g * KR;

    // block-uniform weight-row bases for the two n-halves
    const int n1 = col * 64 + HN;
    const bool h1E = (n1 < NE);
    const float* e0 = W_ee + (size_t)(col * 64) * NE;
    const float* e1 = h1E ? (W_ee + (size_t)n1 * NE) : (W_ei + (size_t)(n1 - NE) * NE);
    const float* i0 = W_ie + (size_t)(col * 64) * NI;
    const float* i1 = h1E ? (W_ie + (size_t)n1 * NI) : (W_ii + (size_t)(n1 - NE) * NI);

    double accA[8], accB[8];
#pragma unroll
    for (int j = 0; j < 8; ++j) { accA[j] = 0.0; accB[j] = 0.0; }

    for (int ch = 0; ch < KR / CHUNK; ++ch) {
        const int kb = kb0 + ch * CHUNK;       // CHUNK|NE -> pure E or I seg
        const bool eseg = (kb < NE);
        const int kloc = eseg ? kb : kb - NE;
        const size_t kdim = eseg ? NE : NI;
        const float* b0 = eseg ? e0 : i0;
        const float* b1 = eseg ? e1 : i1;

        if (ch) __syncthreads();
        // stage 128 rows x 32 k: 16 slots of (64 lanes x 16B); 4 per wave.
#pragma unroll
        for (int c = 0; c < 4; ++c) {
            const int slot = wv * 4 + c;
            const int q = slot >> 1;           // k-quad 0..7
            const float* base = (slot & 1) ? b1 : b0;
            load_lds16(base + (size_t)lane * kdim + (kloc + q * 4),
                       &tile[slot * 256]);
        }
        __syncthreads();

#pragma unroll
        for (int q = 0; q < 8; ++q) {
            const float4 wa = *reinterpret_cast<const float4*>(&tile[(q * 2 + 0) * 256 + lane * 4]);
            const float4 wb = *reinterpret_cast<const float4*>(&tile[(q * 2 + 1) * 256 + lane * 4]);
            const uint4 mq = *reinterpret_cast<const uint4*>(&maskIn[kb + q * 4]);
            const u32 m0 = ((u32)__builtin_amdgcn_readfirstlane(mq.x)) >> jh;
            const u32 m1 = ((u32)__builtin_amdgcn_readfirstlane(mq.y)) >> jh;
            const u32 m2 = ((u32)__builtin_amdgcn_readfirstlane(mq.z)) >> jh;
            const u32 m3 = ((u32)__builtin_amdgcn_readfirstlane(mq.w)) >> jh;

            const double wa0 = (double)wa.x, wa1 = (double)wa.y,
                         wa2 = (double)wa.z, wa3 = (double)wa.w;
            const double wb0 = (double)wb.x, wb1 = (double)wb.y,
                         wb2 = (double)wb.z, wb3 = (double)wb.w;
#pragma unroll
            for (int j = 0; j < 8; ++j) {
                const double s0 = (double)((m0 >> j) & 1u);
                const double s1 = (double)((m1 >> j) & 1u);
                const double s2 = (double)((m2 >> j) & 1u);
                const double s3 = (double)((m3 >> j) & 1u);
                accA[j] += wa0 * s0 + wa1 * s1 + wa2 * s2 + wa3 * s3;
                accB[j] += wb0 * s0 + wb1 * s1 + wb2 * s2 + wb3 * s3;
            }
        }
    }

#pragma unroll
    for (int j = 0; j < 8; ++j) {
        const size_t base = ((size_t)g * BB + jh + j) * NN;
        partial[base + nA] = accA[j];
        partial[base + nA + HN] = accB[j];
    }

    // ---- last-block-wins reduction (canonical fence protocol) ----
    __threadfence();                       // release: my partial stores
    __syncthreads();                       // whole block done storing
    if (tid == 0)
        s_won = (atomicAdd(&cnt[t * NCOL + col], 1) == G - 1) ? 1 : 0;
    __syncthreads();
    if (!s_won) return;
    __threadfence();                       // acquire: see all 32 partials

    if (tid < 128) s_m[tid] = 0u;
    __syncthreads();

    // 128 n (two halves) x 32 b = 4096 elements, 16 per thread (fixed ni)
    const int ni = tid & 127;
    const int n = (ni < 64) ? (col * 64 + ni) : (HN + col * 64 + (ni - 64));
    u32 mbits = 0;
    for (int e = tid; e < 4096; e += 256) {
        const int b = e >> 7;
        const float ext = (n < NE)
            ? ext_exc[((size_t)t * BB + b) * NE + n]
            : ext_inh[((size_t)t * BB + b) * NI + (n - NE)];
        double acc = (double)ext;
#pragma unroll
        for (int g2 = 0; g2 < G; ++g2)
            acc += partial[((size_t)g2 * BB + b) * NN + n];
        const size_t vi = (size_t)b * NN + n;
        const double vv = v[vi] * 0.9 + acc;
        const double sp = (vv > 1.0) ? 1.0 : 0.0;
        out[(size_t)t * BB * NN + vi] = (float)sp;
        v[vi] = vv * (1.0 - sp);
        if (sp != 0.0) mbits |= (1u << b);
    }
    atomicOr(&s_m[ni], mbits);             // LDS OR across the 2 threads/ni
    __syncthreads();
    if (tid < 128) maskOut[n] = s_m[tid];
}

extern "C" void kernel_launch(void* const* d_in, const int* in_sizes, int n_in,
                              void* d_out, int out_size, void* d_ws, size_t ws_size,
                              hipStream_t stream) {
    const float* ext_exc = (const float*)d_in[0];
    const float* ext_inh = (const float*)d_in[1];
    const float* W_ee = (const float*)d_in[2];
    const float* W_ei = (const float*)d_in[3];
    const float* W_ie = (const float*)d_in[4];
    const float* W_ii = (const float*)d_in[5];
    float* out = (float*)d_out;

    const int T = in_sizes[0] / (BB * NE);   // 64

    const size_t SN = (size_t)BB * NN;       // 163840
    double* v = (double*)d_ws;                         // SN*8
    u32* maskA = (u32*)(v + SN);                       // NN*4
    u32* maskB = maskA + NN;                           // NN*4
    int* cnt = (int*)(maskB + NN);                     // T*NCOL*4
    const size_t stateBytes = SN * 8 + (size_t)NN * 8 + (size_t)T * NCOL * 4;
    double* partial = (double*)((char*)d_ws + ((stateBytes + 15) & ~(size_t)15));

    // G=32 preferred (41.9MB partial, proven fit); G=16 fallback
    const size_t base = ((stateBytes + 15) & ~(size_t)15);
    int G = 32;
    if (base + (size_t)G * SN * sizeof(double) > ws_size) G = 16;

    hipMemsetAsync(d_ws, 0, stateBytes, stream);   // v=0, masks=0, cnt=0

    for (int t = 0; t < T; ++t) {
        const u32* mIn  = (t & 1) ? maskB : maskA;
        u32*       mOut = (t & 1) ? maskA : maskB;
        if (G == 32) {
            step_kernel<32><<<dim3(NCOL, 32), 256, 0, stream>>>(
                W_ee, W_ei, W_ie, W_ii, ext_exc, ext_inh,
                mIn, mOut, partial, v, out, cnt, t);
        } else {
            step_kernel<16><<<dim3(NCOL, 16), 256, 0, stream>>>(
                W_ee, W_ei, W_ie, W_ii, ext_exc, ext_inh,
                mIn, mOut, partial, v, out, cnt, t);
        }
    }
}

// Round 15
// 4811.663 us; speedup vs baseline: 2.9024x; 2.9024x over previous
//
#include <hip/hip_runtime.h>

// Recurrent spiking LIF network: T=64, B=32, NE=4096, NI=1024, N=5120.
// fp64 accumulation => spike-identical to fp64 numpy ref (rounds 2-14: 0.0).
//
// Round-15: r13 core with the occupancy fix; fusion (r14) reverted.
//  - mv: G=32 k-split -> grid (40,32) = 1280 blocks = EXACTLY 5/CU
//    (r13 ran G=16 = 2.5/CU at 18.6% occupancy; barrier/vmcnt drains had
//    no co-resident block to hide under). CHUNK=32 -> 16 KB LDS.
//  - weights staged once per tile via global_load_lds (FETCH 51 MB, r13).
//  - spikes as bitmask in SGPRs (readfirstlane), dense bit->f64 fma.
//  - upd: G=32 reduction + LIF (proven r2-r13 form). pack: 20 blocks.

#define NE 4096
#define NI 1024
#define NN 5120
#define HN 2560
#define BB 32
#define CHUNK 32

typedef unsigned int u32;

__device__ __forceinline__ void load_lds16(const float* g, float* l) {
    __builtin_amdgcn_global_load_lds(
        (const __attribute__((address_space(1))) u32*)g,
        (__attribute__((address_space(3))) u32*)l, 16, 0, 0);
}

// ---------------- spike pack kernel ----------------
__global__ __launch_bounds__(256) void pack_kernel(
    const float* __restrict__ out_t, u32* __restrict__ mask)
{
    const int n = blockIdx.x * 256 + threadIdx.x;   // NN = 20*256 exact
    u32 m = 0;
#pragma unroll
    for (int b = 0; b < BB; ++b)
        m |= (out_t[(size_t)b * NN + n] > 0.5f ? 1u : 0u) << b;
    mask[n] = m;
}

// ---------------- matvec partial kernel ----------------
// grid: (HN/64, G), block 256 = 64 n-lanes x 4 j-groups(8 batches).
// Thread owns neurons {nA = bx*64+lane, nA+2560} x batches [jh, jh+8).
template <int G>
__global__ __launch_bounds__(256) void mv_kernel(
    const float* __restrict__ W_ee, const float* __restrict__ W_ei,
    const float* __restrict__ W_ie, const float* __restrict__ W_ii,
    const u32* __restrict__ mask,    // [NN] spike bitmasks (bit b = batch b)
    double* __restrict__ partial)    // [G][BB][NN]
{
    constexpr int KR = NN / G;
    __shared__ __align__(16) float tile[16 * 256];   // 16 slots x 64 lanes x 16B
    const int tid  = threadIdx.x;
    const int lane = tid & 63;
    const int wv   = tid >> 6;
    const int jh   = wv << 3;                  // 0,8,16,24
    const int nA   = blockIdx.x * 64 + lane;   // < HN (E-target half)
    const int kb0  = blockIdx.y * KR;

    // block-uniform weight-row bases for the two n-halves
    const int n0 = blockIdx.x * 64;
    const int n1 = n0 + HN;
    const bool h1E = (n1 < NE);
    const float* e0 = W_ee + (size_t)n0 * NE;
    const float* e1 = h1E ? (W_ee + (size_t)n1 * NE) : (W_ei + (size_t)(n1 - NE) * NE);
    const float* i0 = W_ie + (size_t)n0 * NI;
    const float* i1 = h1E ? (W_ie + (size_t)n1 * NI) : (W_ii + (size_t)(n1 - NE) * NI);

    double accA[8], accB[8];
#pragma unroll
    for (int j = 0; j < 8; ++j) { accA[j] = 0.0; accB[j] = 0.0; }

    for (int ch = 0; ch < KR / CHUNK; ++ch) {
        const int kb = kb0 + ch * CHUNK;       // 32 | NE -> pure E or I segment
        const bool eseg = (kb < NE);
        const int kloc = eseg ? kb : kb - NE;
        const size_t kdim = eseg ? NE : NI;
        const float* b0 = eseg ? e0 : i0;
        const float* b1 = eseg ? e1 : i1;

        if (ch) __syncthreads();               // protect tile overwrite
        // stage 128 rows x 32 k: 16 slots of (64 lanes x 16B); 4 per wave.
        // slot = q*2 + half; lane l stages row l of its half at quad q.
#pragma unroll
        for (int c = 0; c < 4; ++c) {
            const int slot = wv * 4 + c;
            const int q = slot >> 1;
            const float* base = (slot & 1) ? b1 : b0;
            load_lds16(base + (size_t)lane * kdim + (kloc + q * 4),
                       &tile[slot * 256]);
        }
        __syncthreads();                       // drains vmcnt -> tile valid

#pragma unroll
        for (int q = 0; q < 8; ++q) {
            const float4 wa = *reinterpret_cast<const float4*>(&tile[(q * 2 + 0) * 256 + lane * 4]);
            const float4 wb = *reinterpret_cast<const float4*>(&tile[(q * 2 + 1) * 256 + lane * 4]);
            const uint4 mq = *reinterpret_cast<const uint4*>(&mask[kb + q * 4]);
            const u32 m0 = ((u32)__builtin_amdgcn_readfirstlane(mq.x)) >> jh;
            const u32 m1 = ((u32)__builtin_amdgcn_readfirstlane(mq.y)) >> jh;
            const u32 m2 = ((u32)__builtin_amdgcn_readfirstlane(mq.z)) >> jh;
            const u32 m3 = ((u32)__builtin_amdgcn_readfirstlane(mq.w)) >> jh;

            const double wa0 = (double)wa.x, wa1 = (double)wa.y,
                         wa2 = (double)wa.z, wa3 = (double)wa.w;
            const double wb0 = (double)wb.x, wb1 = (double)wb.y,
                         wb2 = (double)wb.z, wb3 = (double)wb.w;
#pragma unroll
            for (int j = 0; j < 8; ++j) {
                const double s0 = (double)((m0 >> j) & 1u);
                const double s1 = (double)((m1 >> j) & 1u);
                const double s2 = (double)((m2 >> j) & 1u);
                const double s3 = (double)((m3 >> j) & 1u);
                accA[j] += wa0 * s0 + wa1 * s1 + wa2 * s2 + wa3 * s3;
                accB[j] += wb0 * s0 + wb1 * s1 + wb2 * s2 + wb3 * s3;
            }
        }
    }

#pragma unroll
    for (int j = 0; j < 8; ++j) {
        const size_t base = ((size_t)blockIdx.y * BB + jh + j) * NN;
        partial[base + nA] = accA[j];
        partial[base + nA + HN] = accB[j];
    }
}

// ---------------- LIF update kernel ----------------
template <int G>
__global__ __launch_bounds__(256) void upd_kernel(
    const float* __restrict__ ext_exc,   // [T][BB][NE]
    const float* __restrict__ ext_inh,   // [T][BB][NI]
    const double* __restrict__ partial,  // [G][BB][NN]
    double* __restrict__ v,              // [BB][NN]
    float* __restrict__ out,             // [T][BB][NN]
    int t)
{
    const int idx = blockIdx.x * 256 + threadIdx.x;   // < BB*NN
    const int b = idx / NN;
    const int n = idx - b * NN;

    const float ext = (n < NE)
        ? ext_exc[((size_t)t * BB + b) * NE + n]
        : ext_inh[((size_t)t * BB + b) * NI + (n - NE)];

    double acc = (double)ext;
#pragma unroll
    for (int g = 0; g < G; ++g)
        acc += partial[((size_t)g * BB + b) * NN + n];

    const double vv = v[idx] * 0.9 + acc;
    const double sp = (vv > 1.0) ? 1.0 : 0.0;
    out[(size_t)t * BB * NN + idx] = (float)sp;
    v[idx] = vv * (1.0 - sp);
}

extern "C" void kernel_launch(void* const* d_in, const int* in_sizes, int n_in,
                              void* d_out, int out_size, void* d_ws, size_t ws_size,
                              hipStream_t stream) {
    const float* ext_exc = (const float*)d_in[0];
    const float* ext_inh = (const float*)d_in[1];
    const float* W_ee = (const float*)d_in[2];
    const float* W_ei = (const float*)d_in[3];
    const float* W_ie = (const float*)d_in[4];
    const float* W_ii = (const float*)d_in[5];
    float* out = (float*)d_out;

    const int T = in_sizes[0] / (BB * NE);   // 64

    const size_t SN = (size_t)BB * NN;       // 163840
    double* v = (double*)d_ws;               // SN*8
    u32* mask = (u32*)(v + SN);              // NN*4
    const size_t stateBytes = SN * 8 + (size_t)NN * 4;   // ~1.33 MB
    double* partial = (double*)((char*)d_ws + stateBytes);

    // G=32 preferred (41.9 MB partial; proven fit in rounds 2/5/9).
    int G = 32;
    if (stateBytes + (size_t)G * SN * sizeof(double) > ws_size) G = 16;

    hipMemsetAsync(d_ws, 0, stateBytes, stream);   // v = 0, mask = 0

    for (int t = 0; t < T; ++t) {
        if (G == 32) {
            mv_kernel<32><<<dim3(HN / 64, 32), 256, 0, stream>>>(
                W_ee, W_ei, W_ie, W_ii, mask, partial);
            upd_kernel<32><<<(int)(SN / 256), 256, 0, stream>>>(
                ext_exc, ext_inh, partial, v, out, t);
        } else {
            mv_kernel<16><<<dim3(HN / 64, 16), 256, 0, stream>>>(
                W_ee, W_ei, W_ie, W_ii, mask, partial);
            upd_kernel<16><<<(int)(SN / 256), 256, 0, stream>>>(
                ext_exc, ext_inh, partial, v, out, t);
        }
        pack_kernel<<<NN / 256, 256, 0, stream>>>(out + (size_t)t * SN, mask);
    }
}